// Round 4
// baseline (1120.340 us; speedup 1.0000x reference)
//
#include <hip/hip_runtime.h>

// ---------------------------------------------------------------------------
// NeuralCA fused step, wave-specialized + 3-stage pipeline, de-phased blocks:
//   2-row blocks, 256 thr = 4 waves (wv0,1 = G1; wv2,3 = G23), 448 blocks,
//   LDS 63.7 KB -> 2 blocks/CU so each SIMD hosts waves of 2 INDEPENDENT
//   blocks (independent barriers fill each other's stalls).
//   G1:  h1 = relu(W_eff * im2col(x) + b1)   W_eff in regs (160 VGPR)
//   G23: iter j: G2 on h1[j-1] -> h2 dbuf;  G3+epilogue on h2[j-2]
//   x = clamp(x + dx, 0, 1)
// Loop barrier = lgkmcnt(0)+s_barrier only (no vmcnt drain).
// bf16 MFMA 16x16x32, fp32 master state (NHWC) + bf16 shadow (NHWC).
// ---------------------------------------------------------------------------

typedef __attribute__((ext_vector_type(8))) short short8;
typedef __attribute__((ext_vector_type(4))) float float4v;

#define MFMA16(a, b, c) __builtin_amdgcn_mfma_f32_16x16x32_bf16((a), (b), (c), 0, 0, 0)

__device__ __forceinline__ short f2bf(float f) {
  unsigned u = __builtin_bit_cast(unsigned, f);
  return (short)((u + 0x8000u) >> 16);     // round-half-up
}

__device__ __forceinline__ void async16(const void* g, void* l) {
  __builtin_amdgcn_global_load_lds((const __attribute__((address_space(1))) void*)g,
                                   (__attribute__((address_space(3))) void*)l,
                                   16, 0, 0);
}

// LDS-only barrier: no vmcnt drain (global stores/loads in flight stay so)
__device__ __forceinline__ void sync_lds() {
  asm volatile("s_waitcnt lgkmcnt(0)\n\ts_barrier" ::: "memory");
}

// ---- workspace layout (bytes) ----
#define WS_WE    0          // W_eff^T [128][168] bf16 (K pad 144->168, zeros)
#define WS_W2    43008      // W2^T    [128][136] bf16 (K sigma-permuted)
#define WS_W3    77824      // W3^T    [ 16][136] bf16 (sigma-perm, pad to 2560)
#define WS_B1    82944      // b1 sigma-permuted f32 [128]
#define WS_B2    83456      // b2 sigma-permuted f32 [128]
#define WS_X32A  83968
#define WS_X32B  12929024
#define WS_X16A  25774080
#define WS_X16B  32196608

// ---------------------------------------------------------------------------
__global__ void prep_x(const float* __restrict__ x, float* __restrict__ x32,
                       short* __restrict__ x16) {
  int i = blockIdx.x * 256 + threadIdx.x;          // exactly 3211264 threads
  int w = i % 224;
  int h = (i / 224) % 224;
  int c = (i / 50176) & 15;
  int bb = i / 802816;
  float v = x[i];
  int o = ((bb * 224 + h) * 224 + w) * 16 + c;     // NHWC
  x32[o] = v;
  x16[o] = f2bf(v);
}

// sigma: stored position p holds channel chan(p) = 16*(p&7) + (p>>3)
__global__ void prep_w(const float* __restrict__ wp, const float* __restrict__ w1,
                       const float* __restrict__ b1, const float* __restrict__ w2,
                       const float* __restrict__ b2, const float* __restrict__ w3,
                       short* __restrict__ wE, short* __restrict__ w2t,
                       short* __restrict__ w3t, float* __restrict__ b1p,
                       float* __restrict__ b2p) {
  int i = blockIdx.x * 256 + threadIdx.x;          // exactly 41728 threads
  if (i < 21504) {                                  // W_eff^T [o=128][k=168]
    int o = i / 168, k = i % 168;
    float v = 0.f;
    if (k < 144) {
      int off = k >> 4, c = k & 15;                 // k = offset*16 + c
      for (int c3 = 0; c3 < 48; ++c3)
        v += w1[o * 48 + c3] * wp[c3 * 144 + c * 9 + off];
    }
    wE[i] = f2bf(v);
  } else if (i < 38912) {                           // W2^T perm [n=128][kk=136]
    int j = i - 21504;
    int n = j / 136, kk = j % 136;
    float v = 0.f;
    if (kk < 128) { int ch = 16 * (kk & 7) + (kk >> 3); v = w2[n * 128 + ch]; }
    w2t[j] = f2bf(v);
  } else if (i < 41472) {                           // W3^T perm, padded to 2560
    int j = i - 38912;
    float v = 0.f;
    if (j < 2176) {
      int n = j / 136, kk = j % 136;
      if (kk < 128) { int ch = 16 * (kk & 7) + (kk >> 3); v = w3[n * 128 + ch]; }
    }
    w3t[j] = f2bf(v);
  } else if (i < 41600) {
    int p = i - 41472;
    b1p[p] = b1[16 * (p & 7) + (p >> 3)];
  } else {
    int p = i - 41600;
    b2p[p] = b2[16 * (p & 7) + (p >> 3)];
  }
}

// ---------------------------------------------------------------------------
// One CA step. Block = 2 image rows of one batch, 256 threads = 4 waves.
// 28 M-tiles (16 px each); pipeline over 16 iterations:
//   G1 wave w (wv=w):   iter j (<14)  : h1 of tile 2j+w     -> mailbox j&1
//   G23 wave g (wv=2+g): iter j (1..14): G2 of tile 2(j-1)+g -> h2 dbuf j&1
//                        iter j (2..15): G3+epilogue of tile 2(j-2)+g
template <bool LAST>
__global__ __launch_bounds__(256, 2) void ca_step(
    const short* __restrict__ wEg, const short* __restrict__ w2g,
    const short* __restrict__ w3g, const float* __restrict__ b1p,
    const float* __restrict__ b2p, const float* __restrict__ xs32,
    const short* __restrict__ xs16, float* __restrict__ xd32,
    short* __restrict__ xd16, float* __restrict__ dout) {
  __shared__ short sXH[4 * 3616];       // 28928 B  halo: 4 rows x 226 x 16ch
  __shared__ short sBUF[2 * 2 * 2176];  // 17408 B  h1 mailbox, dbuf x 2 slots
  __shared__ short sH2[2 * 2 * 2176];   // 17408 B  per-wave h2 double buffer
  // total 63744 B -> 2 blocks/CU, 8 waves/CU from 2 independent blocks

  const int tid = threadIdx.x;
  const int lane = tid & 63;
  const int wv = tid >> 6;
  const int c16 = lane & 15;
  const int q = lane >> 4;
  const int q8 = q * 8;
  const int qh = q >> 1;
  const int c0 = (q & 1) * 8;

  const int blk = blockIdx.x;           // 448 blocks = 4 batches x 112 rowgroups
  const int b = blk / 112;
  const int h0 = (blk % 112) * 2;

  // ---- stage halo: 4 rows x 7 chunks (1KB each); OOB rows -> zeros ----
  const short8 z8 = {0, 0, 0, 0, 0, 0, 0, 0};
  for (int t = wv; t < 28; t += 4) {
    int hr = t / 7, ck = t % 7;
    int hh = h0 - 1 + hr;
    char* l = (char*)sXH + hr * 7232 + 32 + ck * 1024;  // col 0 = image col -1
    if (hh >= 0 && hh < 224) {
      const char* g = (const char*)xs16 + ((size_t)(b * 224 + hh) * 224) * 32 + ck * 1024;
      async16(g + lane * 16, l);
    } else {
      *(short8*)(l + lane * 16) = z8;
    }
  }
  if (tid < 16) {   // zero edge columns (image col -1 and 224) for all 4 rows
    int hr = tid >> 2, wch = tid & 3;
    int colb = (wch < 2) ? 0 : 225;
    *(short8*)((char*)sXH + hr * 7232 + colb * 32 + (wch & 1) * 16) = z8;
  }

  if (wv < 2) {
    // ================= G1 waves: conv3x3+MLP1 fused ======================
    short8 wf[5][8];                    // 160 VGPR: W_eff fragments
#pragma unroll
    for (int kc = 0; kc < 5; ++kc)
#pragma unroll
      for (int nt = 0; nt < 8; ++nt)
        wf[kc][nt] = *(const short8*)(wEg + (nt * 16 + c16) * 168 + kc * 32 + q8);
    const float4v bA = *(const float4v*)(b1p + c16 * 8);
    const float4v bB = *(const float4v*)(b1p + c16 * 8 + 4);

    __syncthreads();                    // halo ready (drains vmcnt)

    for (int j = 0; j < 16; ++j) {
      if (j < 14) {
        const int t = 2 * j + wv;
        const int rr = t / 14, cb = (t % 14) * 16;
        const int hbase = (rr * 226 + cb) * 16;
        float4v acc[8];
#pragma unroll
        for (int nt = 0; nt < 8; ++nt) acc[nt] = (float4v){0.f, 0.f, 0.f, 0.f};
#pragma unroll
        for (int kc = 0; kc < 5; ++kc) {
          int off = kc * 2 + qh;
          if (off > 8) off = 8;         // K 144..159 hit zero rows of W_eff
          int dy = (off * 11) >> 5;     // off/3
          int dxx = off - dy * 3;
          short8 a = *(const short8*)(sXH + hbase + (dy * 226 + dxx + c16) * 16 + c0);
#pragma unroll
          for (int nt = 0; nt < 8; ++nt) acc[nt] = MFMA16(a, wf[kc][nt], acc[nt]);
        }
        short* dst = sBUF + ((j & 1) * 2 + wv) * 2176;
#pragma unroll
        for (int r = 0; r < 4; ++r) {
          short8 pk;
#pragma unroll
          for (int nt = 0; nt < 8; ++nt) {
            float v = acc[nt][r] + ((nt < 4) ? bA[nt] : bB[nt - 4]);
            pk[nt] = f2bf(fmaxf(v, 0.f));
          }
          *(short8*)(dst + (q * 4 + r) * 136 + c16 * 8) = pk;
        }
      }
      sync_lds();
    }
  } else {
    // ========= G23 waves: MLP2 (tile j-1) + MLP3/update (tile j-2) =======
    short8 w2f[4][8];                   // 128 VGPR
    short8 w3f[4];                      //  16 VGPR
#pragma unroll
    for (int kc = 0; kc < 4; ++kc)
#pragma unroll
      for (int nt = 0; nt < 8; ++nt)
        w2f[kc][nt] = *(const short8*)(w2g + (nt * 16 + c16) * 136 + kc * 32 + q8);
#pragma unroll
    for (int kc = 0; kc < 4; ++kc)
      w3f[kc] = *(const short8*)(w3g + c16 * 136 + kc * 32 + q8);
    const float4v bA = *(const float4v*)(b2p + c16 * 8);
    const float4v bB = *(const float4v*)(b2p + c16 * 8 + 4);

    const int g = wv - 2;

    __syncthreads();                    // halo ready

    for (int j = 0; j < 16; ++j) {
      // ---- prefetch residual x for the tile G3 finishes this iter ----
      float xres[4];
      int cb3 = 0, hglob3 = 0;
      if (j >= 2) {
        const int t3 = 2 * (j - 2) + g;
        cb3 = (t3 % 14) * 16; hglob3 = h0 + t3 / 14;
#pragma unroll
        for (int r = 0; r < 4; ++r) {
          size_t pix = (size_t)(b * 224 + hglob3) * 224 + cb3 + q * 4 + r;
          xres[r] = xs32[pix * 16 + c16];
        }
      }
      // ---- G2: consume h1 mailbox -> h2 dbuf (private, no barrier) ----
      if (j >= 1 && j <= 14) {
        const short* src = sBUF + (((j - 1) & 1) * 2 + g) * 2176;
        float4v acc2[8];
#pragma unroll
        for (int nt = 0; nt < 8; ++nt) acc2[nt] = (float4v){0.f, 0.f, 0.f, 0.f};
#pragma unroll
        for (int kc = 0; kc < 4; ++kc) {
          short8 a = *(const short8*)(src + c16 * 136 + kc * 32 + q8);
#pragma unroll
          for (int nt = 0; nt < 8; ++nt) acc2[nt] = MFMA16(a, w2f[kc][nt], acc2[nt]);
        }
        short* dsth2 = sH2 + ((j & 1) * 2 + g) * 2176;
#pragma unroll
        for (int r = 0; r < 4; ++r) {
          short8 pk;
#pragma unroll
          for (int nt = 0; nt < 8; ++nt) {
            float v = acc2[nt][r] + ((nt < 4) ? bA[nt] : bB[nt - 4]);
            pk[nt] = f2bf(fmaxf(v, 0.f));
          }
          *(short8*)(dsth2 + (q * 4 + r) * 136 + c16 * 8) = pk;
        }
      }
      // ---- G3 + epilogue on h2 written LAST iter (slot (j-1)&1) ----
      if (j >= 2) {
        const short* srch2 = sH2 + (((j - 1) & 1) * 2 + g) * 2176;
        float4v acc3 = (float4v){0.f, 0.f, 0.f, 0.f};
#pragma unroll
        for (int kc = 0; kc < 4; ++kc) {
          short8 a = *(const short8*)(srch2 + c16 * 136 + kc * 32 + q8);
          acc3 = MFMA16(a, w3f[kc], acc3);
        }
#pragma unroll
        for (int r = 0; r < 4; ++r) {
          int col = cb3 + q * 4 + r;
          size_t pix = (size_t)(b * 224 + hglob3) * 224 + col;
          float v = xres[r] + acc3[r];
          v = fminf(fmaxf(v, 0.f), 1.f);
          if (LAST) {
            dout[((size_t)(b * 16 + c16) * 224 + hglob3) * 224 + col] = v;  // NCHW
          } else {
            xd32[pix * 16 + c16] = v;
            xd16[pix * 16 + c16] = f2bf(v);
          }
        }
      }
      sync_lds();
    }
  }
}

// ---------------------------------------------------------------------------
extern "C" void kernel_launch(void* const* d_in, const int* in_sizes, int n_in,
                              void* d_out, int out_size, void* d_ws, size_t ws_size,
                              hipStream_t stream) {
  const float* x  = (const float*)d_in[0];
  const float* wp = (const float*)d_in[1];
  const float* w1 = (const float*)d_in[2];
  const float* b1 = (const float*)d_in[3];
  const float* w2 = (const float*)d_in[4];
  const float* b2 = (const float*)d_in[5];
  const float* w3 = (const float*)d_in[6];

  char* ws = (char*)d_ws;
  short* wEg = (short*)(ws + WS_WE);
  short* w2g = (short*)(ws + WS_W2);
  short* w3g = (short*)(ws + WS_W3);
  float* b1p = (float*)(ws + WS_B1);
  float* b2p = (float*)(ws + WS_B2);
  float* X32[2] = {(float*)(ws + WS_X32A), (float*)(ws + WS_X32B)};
  short* X16[2] = {(short*)(ws + WS_X16A), (short*)(ws + WS_X16B)};

  prep_x<<<12544, 256, 0, stream>>>(x, X32[0], X16[0]);
  prep_w<<<163, 256, 0, stream>>>(wp, w1, b1, w2, b2, w3, wEg, w2g, w3g, b1p, b2p);

  for (int s = 0; s < 39; ++s) {
    int sb = s & 1;
    ca_step<false><<<448, 256, 0, stream>>>(wEg, w2g, w3g, b1p, b2p,
                                            X32[sb], X16[sb],
                                            X32[1 - sb], X16[1 - sb], nullptr);
  }
  ca_step<true><<<448, 256, 0, stream>>>(wEg, w2g, w3g, b1p, b2p,
                                         X32[1], X16[1],
                                         X32[0], X16[0], (float*)d_out);
}